// Round 1
// baseline (395.515 us; speedup 1.0000x reference)
//
#include <hip/hip_runtime.h>

// Problem constants
#define B_  4
#define S_  2048
#define D_  1024
#define H_  16
#define DH_ 64
#define M_  (B_*S_)   // 8192

typedef __bf16 bf8_t __attribute__((ext_vector_type(8)));
typedef float f4_t __attribute__((ext_vector_type(4)));
typedef unsigned short u16x8_t __attribute__((ext_vector_type(8)));

static __device__ __forceinline__ unsigned short f2bf(float f) {
  return __builtin_bit_cast(unsigned short, (__bf16)f);
}
static __device__ __forceinline__ bf8_t ldbf8(const unsigned short* p) {
  return __builtin_bit_cast(bf8_t, *(const u16x8_t*)p);
}
#define MFMA16(a,b,c) __builtin_amdgcn_mfma_f32_16x16x32_bf16((a),(b),(c),0,0,0)
#define GLDS16(gp, lp) __builtin_amdgcn_global_load_lds( \
    (const __attribute__((address_space(1))) void*)(gp), \
    (__attribute__((address_space(3))) void*)(lp), 16, 0, 0)

// ---------------- convert kernels ----------------

__global__ void cvt_x(const float* __restrict__ x, unsigned short* __restrict__ xb) {
  int i = blockIdx.x * 256 + threadIdx.x;            // over M_*D_/4
  float4 v = ((const float4*)x)[i];
  unsigned int lo = f2bf(v.x) | ((unsigned int)f2bf(v.y) << 16);
  unsigned int hi = f2bf(v.z) | ((unsigned int)f2bf(v.w) << 16);
  ((uint2*)xb)[i] = make_uint2(lo, hi);
}

// Wq/Wk/Wv are (H, D, DH). Build fused B^T weight: Wcat[n][k], n = qkv*1024 + h*64 + dh, k = d.
__global__ void cvt_wqkv(const float* __restrict__ Wq, const float* __restrict__ Wk,
                         const float* __restrict__ Wv, unsigned short* __restrict__ Wcat) {
  int i = blockIdx.x * 256 + threadIdx.x;            // over 3*1024*1024
  int qkv = i >> 20;
  int r   = i & ((1 << 20) - 1);
  int h   = r >> 16;
  int k   = (r & 65535) >> 6;
  int dh  = r & 63;
  const float* W = (qkv == 0) ? Wq : (qkv == 1 ? Wk : Wv);
  float v = W[r];                                    // r == h*65536 + k*64 + dh
  int n = qkv * 1024 + h * 64 + dh;
  Wcat[(size_t)n * 1024 + k] = f2bf(v);
}

// Wo is (D, D) row-major [d][n]. Build Wot[n][k=d].
__global__ void cvt_wo(const float* __restrict__ Wo, unsigned short* __restrict__ Wot) {
  int i = blockIdx.x * 256 + threadIdx.x;            // over 1024*1024
  int k = i >> 10, n = i & 1023;
  Wot[(size_t)n * 1024 + k] = f2bf(Wo[i]);
}

// ---------------- GEMM core (128x128 tile, BK=32, K=1024, B^T input) ----------------
// LDS tiles are [row][32 shorts]; granules (16B) XOR-swizzled: stored pos p holds
// global granule p ^ ((row>>1)&3) so MFMA fragment reads spread across banks.

static __device__ __forceinline__ void gemm_core(const unsigned short* __restrict__ A,
    const unsigned short* __restrict__ Bt, unsigned short* As, unsigned short* Bs,
    int bm, int bn, f4_t acc[4][4])
{
  const int tid = threadIdx.x, w = tid >> 6, lane = tid & 63;
  const int quad = lane >> 4, col = lane & 15;
  const int wm = (w >> 1) * 64, wn = (w & 1) * 64;
  const int srow = lane >> 2;                         // 0..15
  const int goff = (((lane & 3) ^ ((srow >> 1) & 3)) * 8);
  const unsigned short* ga = A  + (size_t)(bm + 32 * w + srow) * D_ + goff;
  const unsigned short* gb = Bt + (size_t)(bn + 32 * w + srow) * D_ + goff;
  unsigned short* lAs0 = &As[(32 * w) * 32];
  unsigned short* lAs1 = &As[(32 * w + 16) * 32];
  unsigned short* lBs0 = &Bs[(32 * w) * 32];
  unsigned short* lBs1 = &Bs[(32 * w + 16) * 32];
  const int psw = (quad ^ ((col >> 1) & 3)) * 8;

  for (int k0 = 0; k0 < D_; k0 += 32) {
    __syncthreads();
    GLDS16(ga + k0,           lAs0);
    GLDS16(ga + 16 * D_ + k0, lAs1);
    GLDS16(gb + k0,           lBs0);
    GLDS16(gb + 16 * D_ + k0, lBs1);
    __syncthreads();
    bf8_t af[4], bfv[4];
#pragma unroll
    for (int mt = 0; mt < 4; mt++) af[mt]  = ldbf8(&As[(wm + 16 * mt + col) * 32 + psw]);
#pragma unroll
    for (int nt = 0; nt < 4; nt++) bfv[nt] = ldbf8(&Bs[(wn + 16 * nt + col) * 32 + psw]);
#pragma unroll
    for (int mt = 0; mt < 4; mt++)
#pragma unroll
      for (int nt = 0; nt < 4; nt++)
        acc[mt][nt] = MFMA16(af[mt], bfv[nt], acc[mt][nt]);
  }
}

// ---------------- stage 1: QKV projection ----------------
// C[m][n]: m=(b,s), n = qkv*1024 + h*64 + dh. Writes Q,K as (b,h,s,dh); V as (b,h,dh,s).

__global__ __launch_bounds__(256, 2) void gemm_qkv(const unsigned short* __restrict__ A,
    const unsigned short* __restrict__ Bt,
    unsigned short* __restrict__ Qp, unsigned short* __restrict__ Kp,
    unsigned short* __restrict__ Vtp)
{
  __shared__ __align__(16) unsigned short As[128 * 32];
  __shared__ __align__(16) unsigned short Bs[128 * 32];
  f4_t acc[4][4] = {};
  const int bm = blockIdx.y * 128, bn = blockIdx.x * 128;
  gemm_core(A, Bt, As, Bs, bm, bn, acc);

  const int tid = threadIdx.x, w = tid >> 6, lane = tid & 63;
  const int quad = lane >> 4, col = lane & 15;
  const int wm = (w >> 1) * 64, wn = (w & 1) * 64;
#pragma unroll
  for (int nt = 0; nt < 4; nt++) {
    int n = bn + wn + 16 * nt + col;
    int qkv = n >> 10, r1 = n & 1023, h = r1 >> 6, dh = r1 & 63;
#pragma unroll
    for (int mt = 0; mt < 4; mt++) {
      int m0 = bm + wm + 16 * mt + quad * 4;
      int b = m0 >> 11, s0 = m0 & 2047;
      if (qkv == 0) {
#pragma unroll
        for (int r = 0; r < 4; r++)
          Qp[((size_t)(b * H_ + h) * S_ + s0 + r) * DH_ + dh] = f2bf(acc[mt][nt][r]);
      } else if (qkv == 1) {
#pragma unroll
        for (int r = 0; r < 4; r++)
          Kp[((size_t)(b * H_ + h) * S_ + s0 + r) * DH_ + dh] = f2bf(acc[mt][nt][r]);
      } else {
        unsigned int lo = f2bf(acc[mt][nt][0]) | ((unsigned int)f2bf(acc[mt][nt][1]) << 16);
        unsigned int hi = f2bf(acc[mt][nt][2]) | ((unsigned int)f2bf(acc[mt][nt][3]) << 16);
        *(uint2*)&Vtp[((size_t)(b * H_ + h) * DH_ + dh) * S_ + s0] = make_uint2(lo, hi);
      }
    }
  }
}

// ---------------- stage 2: flash attention ----------------
// Block = 128 Q-rows of one (b,h); wave w owns q-rows [32w,32w+32).
// Ks [sk][dh] (128x64), Vs [dh][sk] (64x128), Ps wave-private [32][128].
// All LDS tiles XOR-granule-swizzled (row stride is 128B/256B -> would be 16-way conflicted).

__global__ __launch_bounds__(256, 2) void flash_attn(const unsigned short* __restrict__ Qp,
    const unsigned short* __restrict__ Kp, const unsigned short* __restrict__ Vtp,
    unsigned short* __restrict__ Cc)
{
  __shared__ __align__(16) unsigned short Ks[128 * 64];
  __shared__ __align__(16) unsigned short Vs[64 * 128];
  __shared__ __align__(16) unsigned short Ps[4][32 * 128];
  const int tid = threadIdx.x, w = tid >> 6, lane = tid & 63;
  const int quad = lane >> 4, col = lane & 15;
  const int qt = blockIdx.x, bh = blockIdx.y;

  // Q fragments straight from global (A-layout: row = lane&15, k contiguous)
  const unsigned short* Qg = Qp + ((size_t)bh * S_ + qt * 128 + w * 32) * DH_;
  bf8_t aq[2][2];
#pragma unroll
  for (int t = 0; t < 2; t++)
#pragma unroll
    for (int kc = 0; kc < 2; kc++)
      aq[t][kc] = ldbf8(Qg + (t * 16 + col) * DH_ + kc * 32 + quad * 8);

  f4_t o[2][4] = {};
  float mrow[2][4], lrow[2][4];
#pragma unroll
  for (int t = 0; t < 2; t++)
#pragma unroll
    for (int r = 0; r < 4; r++) { mrow[t][r] = -1e30f; lrow[t][r] = 0.f; }

  const unsigned short* Kg0 = Kp  + (size_t)bh * S_ * DH_;
  const unsigned short* Vg0 = Vtp + (size_t)bh * DH_ * S_;

  for (int kt = 0; kt < S_ / 128; kt++) {
    __syncthreads();
    {
      const unsigned short* Kg = Kg0 + kt * 128 * DH_;
#pragma unroll
      for (int j = 0; j < 4; j++) {                       // K tile: 8 rows/instr
        int row = 32 * w + 8 * j + (lane >> 3);
        GLDS16(Kg + row * DH_ + (((lane & 7) ^ (row & 7)) * 8), &Ks[(32 * w + 8 * j) * 64]);
      }
#pragma unroll
      for (int j = 0; j < 4; j++) {                       // V^T tile: 4 rows/instr
        int row = 16 * w + 4 * j + (lane >> 4);
        GLDS16(Vg0 + (size_t)row * S_ + kt * 128 + (((lane & 15) ^ (row & 15)) * 8),
               &Vs[(16 * w + 4 * j) * 128]);
      }
    }
    __syncthreads();

    // S = Q K^T (scaled later); sc[t][ct] covers q-rows t*16.., k-cols ct*16..
    f4_t sc[2][8] = {};
#pragma unroll
    for (int ct = 0; ct < 8; ct++) {
      int krow = ct * 16 + col;
#pragma unroll
      for (int kc = 0; kc < 2; kc++) {
        bf8_t bk = ldbf8(&Ks[krow * 64 + (((kc * 4 + quad) ^ (krow & 7)) * 8)]);
        sc[0][ct] = MFMA16(aq[0][kc], bk, sc[0][ct]);
        sc[1][ct] = MFMA16(aq[1][kc], bk, sc[1][ct]);
      }
    }

    // online softmax (fp32), P -> wave-private LDS (bf16, swizzled)
#pragma unroll
    for (int t = 0; t < 2; t++) {
#pragma unroll
      for (int r = 0; r < 4; r++) {
        float mx = -1e30f;
#pragma unroll
        for (int ct = 0; ct < 8; ct++) {
          float v = sc[t][ct][r] * 0.125f;                // 1/sqrt(64)
          sc[t][ct][r] = v;
          mx = fmaxf(mx, v);
        }
#pragma unroll
        for (int off = 1; off < 16; off <<= 1) mx = fmaxf(mx, __shfl_xor(mx, off));
        float mold = mrow[t][r];
        float mnew = fmaxf(mold, mx);
        float alpha = __expf(mold - mnew);
        mrow[t][r] = mnew;
        float ps = 0.f;
        int rho = t * 16 + quad * 4 + r;
        unsigned short* Pw = &Ps[w][0];
#pragma unroll
        for (int ct = 0; ct < 8; ct++) {
          float p = __expf(sc[t][ct][r] - mnew);
          ps += p;
          int g = ct * 2 + (col >> 3);
          Pw[rho * 128 + ((g ^ (quad * 4 + r)) * 8) + (col & 7)] = f2bf(p);
        }
#pragma unroll
        for (int off = 1; off < 16; off <<= 1) ps += __shfl_xor(ps, off);
        lrow[t][r] = lrow[t][r] * alpha + ps;
#pragma unroll
        for (int cv = 0; cv < 4; cv++) o[t][cv][r] *= alpha;
      }
    }

    // O += P V  (A = P from LDS, B = V^T rows from Vs)
#pragma unroll
    for (int kc2 = 0; kc2 < 4; kc2++) {
      bf8_t ap0 = ldbf8(&Ps[w][(0 * 16 + col) * 128 + (((kc2 * 4 + quad) ^ col) * 8)]);
      bf8_t ap1 = ldbf8(&Ps[w][(1 * 16 + col) * 128 + (((kc2 * 4 + quad) ^ col) * 8)]);
#pragma unroll
      for (int cv = 0; cv < 4; cv++) {
        int vr = cv * 16 + col;
        bf8_t bv = ldbf8(&Vs[vr * 128 + (((kc2 * 4 + quad) ^ col) * 8)]);
        o[0][cv] = MFMA16(ap0, bv, o[0][cv]);
        o[1][cv] = MFMA16(ap1, bv, o[1][cv]);
      }
    }
  }

  // epilogue: O/l -> concat (b, s, h*64+dh) bf16
  const int b = bh >> 4, h = bh & 15;
#pragma unroll
  for (int t = 0; t < 2; t++)
#pragma unroll
    for (int cv = 0; cv < 4; cv++)
#pragma unroll
      for (int r = 0; r < 4; r++) {
        float v = o[t][cv][r] / lrow[t][r];
        int s = qt * 128 + w * 32 + t * 16 + quad * 4 + r;
        int dcol = h * 64 + cv * 16 + col;
        Cc[((size_t)b * S_ + s) * D_ + dcol] = f2bf(v);
      }
}

// ---------------- stage 3: output projection ----------------

__global__ __launch_bounds__(256, 2) void gemm_out(const unsigned short* __restrict__ A,
    const unsigned short* __restrict__ Bt, float* __restrict__ Out)
{
  __shared__ __align__(16) unsigned short As[128 * 32];
  __shared__ __align__(16) unsigned short Bs[128 * 32];
  f4_t acc[4][4] = {};
  const int bm = blockIdx.y * 128, bn = blockIdx.x * 128;
  gemm_core(A, Bt, As, Bs, bm, bn, acc);

  const int tid = threadIdx.x, w = tid >> 6, lane = tid & 63;
  const int quad = lane >> 4, col = lane & 15;
  const int wm = (w >> 1) * 64, wn = (w & 1) * 64;
#pragma unroll
  for (int nt = 0; nt < 4; nt++) {
    int n = bn + wn + 16 * nt + col;
#pragma unroll
    for (int mt = 0; mt < 4; mt++) {
      int m0 = bm + wm + 16 * mt + quad * 4;
#pragma unroll
      for (int r = 0; r < 4; r++)
        Out[(size_t)(m0 + r) * D_ + n] = acc[mt][nt][r];
    }
  }
}

// ---------------- launch ----------------

extern "C" void kernel_launch(void* const* d_in, const int* in_sizes, int n_in,
                              void* d_out, int out_size, void* d_ws, size_t ws_size,
                              hipStream_t stream) {
  const float* x  = (const float*)d_in[0];
  const float* Wq = (const float*)d_in[1];
  const float* Wk = (const float*)d_in[2];
  const float* Wv = (const float*)d_in[3];
  const float* Wo = (const float*)d_in[4];
  float* out = (float*)d_out;

  char* ws = (char*)d_ws;
  size_t off = 0;
  auto alloc = [&](size_t bytes) -> void* {
    void* p = ws + off;
    off += (bytes + 255) & ~(size_t)255;
    return p;
  };
  unsigned short* xb   = (unsigned short*)alloc((size_t)M_ * D_ * 2);       // 16 MB
  unsigned short* Wcat = (unsigned short*)alloc((size_t)3 * D_ * D_ * 2);   // 6 MB
  unsigned short* Wot  = (unsigned short*)alloc((size_t)D_ * D_ * 2);       // 2 MB
  unsigned short* Qb   = (unsigned short*)alloc((size_t)B_ * H_ * S_ * DH_ * 2); // 16 MB
  unsigned short* Kb   = (unsigned short*)alloc((size_t)B_ * H_ * S_ * DH_ * 2); // 16 MB
  unsigned short* Vtb  = (unsigned short*)alloc((size_t)B_ * H_ * S_ * DH_ * 2); // 16 MB
  unsigned short* Cc   = (unsigned short*)alloc((size_t)M_ * D_ * 2);       // 16 MB
  // total ~88 MB of d_ws

  cvt_x   <<<M_ * D_ / 4 / 256, 256, 0, stream>>>(x, xb);
  cvt_wqkv<<<3 * D_ * D_ / 256, 256, 0, stream>>>(Wq, Wk, Wv, Wcat);
  cvt_wo  <<<D_ * D_ / 256,     256, 0, stream>>>(Wo, Wot);
  gemm_qkv<<<dim3(3 * D_ / 128, M_ / 128), 256, 0, stream>>>(xb, Wcat, Qb, Kb, Vtb);
  flash_attn<<<dim3(S_ / 128, B_ * H_), 256, 0, stream>>>(Qb, Kb, Vtb, Cc);
  gemm_out<<<dim3(D_ / 128, M_ / 128), 256, 0, stream>>>(Cc, Wot, out);
}